// Round 7
// baseline (327.250 us; speedup 1.0000x reference)
//
#include <hip/hip_runtime.h>
#include <math.h>

// Problem constants: E=1,000,000  R=1000  D=200  N_BATCH=50,000  N_TOTAL=100,000
#define DD     200
#define DD3    600
#define MAXBUK 16000   // R*2*NGP upper bound (LDS histogram size)

typedef unsigned int   uint32;
typedef unsigned short uint16;

static __device__ inline float bf2f(uint16 u) {
    union { uint32 i; float f; } x; x.i = ((uint32)u) << 16; return x.f;
}
static __device__ inline uint16 f2bf(float f) {
    union { float f; uint32 i; } x; x.f = f;
    return (uint16)((x.i + 0x7FFFu + ((x.i >> 16) & 1u)) >> 16);
}
static __device__ inline float asf(uint32 u) {
    union { uint32 i; float f; } x; x.i = u; return x.f;
}
static __device__ inline uint32 packbf(float a, float b) {
    return (uint32)f2bf(a) | ((uint32)f2bf(b) << 16);
}

// ---------------- zero int counters (grid-stride) ----------------
__global__ void zero_kernel(int* __restrict__ cnt, int n) {
    int stride = gridDim.x * blockDim.x;
    for (int i = blockIdx.x * blockDim.x + threadIdx.x; i < n; i += stride) cnt[i] = 0;
}

// ---------------- zero float buffer ----------------
__global__ void zerof_kernel(float* __restrict__ p, int n) {
    int stride = gridDim.x * blockDim.x;
    for (int i = blockIdx.x * blockDim.x + threadIdx.x; i < n; i += stride) p[i] = 0.f;
}

// -------- hist over (relation, side, slot>>SSHIFT): nbuk bins, LDS-staged --------
__launch_bounds__(1024)
__global__ void hist6_kernel(const int* __restrict__ etype, const int* __restrict__ eidx,
                             int* __restrict__ cnt, int E, int SSHIFT, int NGP, int nbuk) {
    __shared__ int lc[MAXBUK];
    for (int i = threadIdx.x; i < nbuk; i += 1024) lc[i] = 0;
    __syncthreads();
    int per = (E + gridDim.x - 1) / gridDim.x;
    int beg = blockIdx.x * per;
    int end = min(E, beg + per);
    for (int e = beg + (int)threadIdx.x; e < end; e += 1024) {
        int r  = etype[e];
        int gS = eidx[e] >> SSHIFT;
        int gD = eidx[E + e] >> SSHIFT;
        atomicAdd(&lc[r * (2 * NGP) + gS], 1);
        atomicAdd(&lc[r * (2 * NGP) + NGP + gD], 1);
    }
    __syncthreads();
    for (int i = threadIdx.x; i < nbuk; i += 1024)
        if (lc[i]) atomicAdd(&cnt[i], lc[i]);
}

// ---- exclusive scan, single block, 16/thread + one 1024-wide block scan ----
__launch_bounds__(1024)
__global__ void scan6_kernel(const int* __restrict__ cnt, int* __restrict__ offs,
                             int* __restrict__ cursor, int n) {
    __shared__ int s[1024];
    int tid = threadIdx.x;
    int base = tid * 16;
    int v[16];
    int sum = 0;
    #pragma unroll
    for (int i = 0; i < 16; ++i) {
        int idx = base + i;
        v[i] = (idx < n) ? cnt[idx] : 0;
        sum += v[i];
    }
    s[tid] = sum;
    for (int off = 1; off < 1024; off <<= 1) {
        __syncthreads();
        int t = (tid >= off) ? s[tid - off] : 0;
        __syncthreads();
        s[tid] += t;
    }
    __syncthreads();
    int excl = s[tid] - sum;
    #pragma unroll
    for (int i = 0; i < 16; ++i) {
        int idx = base + i;
        if (idx < n) { offs[idx] = excl; cursor[idx] = excl; }
        excl += v[i];
    }
    if (tid == 1023) offs[n] = excl;
}

// -------- scatter: slot (uint16) into (r, side, group) buckets --------
__global__ void scatter6_kernel(const int* __restrict__ etype, const int* __restrict__ eidx,
                                int* __restrict__ cursor, uint16* __restrict__ list,
                                int E, int SSHIFT, int NGP) {
    int stride = gridDim.x * blockDim.x;
    for (int i = blockIdx.x * blockDim.x + threadIdx.x; i < E; i += stride) {
        int r  = etype[i];
        int sS = eidx[i];
        int sD = eidx[E + i];
        int pS = atomicAdd(&cursor[r * (2 * NGP) + (sS >> SSHIFT)], 1);
        list[pS] = (uint16)sS;
        int pD = atomicAdd(&cursor[r * (2 * NGP) + NGP + (sD >> SSHIFT)], 1);
        list[pD] = (uint16)sD;
    }
}

// -------- compact: cmp[slot][u] (100 uint32 = 400B bf16 row), float4 reads --------
__global__ void compact6_kernel(const int* __restrict__ node_id,
                                const float* __restrict__ emb,
                                uint32* __restrict__ cmp, int NB) {
    int idx = blockIdx.x * blockDim.x + threadIdx.x;
    if (idx >= NB * 50) return;
    int s = idx / 50, q = idx - s * 50;        // q in [0,50): dims 4q..4q+3
    int nid = node_id[s];
    float4 v = *(const float4*)(emb + (size_t)nid * DD + 4 * q);
    *(uint2*)(cmp + (size_t)s * 100 + 2 * q) = make_uint2(packbf(v.x, v.y), packbf(v.z, v.w));
}

// ---------------- fused transpose of both W (rows x cols) -> WT (cols x rows) ----------------
__global__ void transpose2_kernel(const float* __restrict__ A, const float* __restrict__ B,
                                  float* __restrict__ TA, float* __restrict__ TB,
                                  int rows, int cols) {
    int idx = blockIdx.x * blockDim.x + threadIdx.x;
    int n = rows * cols;
    if (idx < n) {
        int j = idx / cols, d = idx % cols;
        TA[d * rows + j] = A[idx];
    } else if (idx < 2 * n) {
        int k = idx - n;
        int j = k / cols, d = k % cols;
        TB[d * rows + j] = B[k];
    }
}

// -------- partial sums: block = bucket b; b&7 = slot-group -> XCD-local slice --------
// Full 400B rows; 2 entries per wave (lanes 0-24 entry A, 25-49 entry B, uint4/lane).
__launch_bounds__(256)
__global__ void partial6_kernel(const uint16* __restrict__ list,
                                const uint32* __restrict__ cmp,
                                const int* __restrict__ offs,
                                uint16* __restrict__ partial) {  // (nbuk, 200) bf16 sums
    const int b    = blockIdx.x;
    const int tid  = threadIdx.x;
    const int w    = tid >> 6;
    const int lane = tid & 63;
    const int sub  = lane / 25;        // 0: entry A, 1: entry B, 2: idle
    const int w25  = lane % 25;        // uint4 index within row

    __shared__ float red[8][DD];

    const int beg = offs[b];
    const int end = offs[b + 1];
    const int laneOff = w25 * 4;       // uint32 offset within row

    float a0 = 0.f, a1 = 0.f, a2 = 0.f, a3 = 0.f, a4 = 0.f, a5 = 0.f, a6 = 0.f, a7 = 0.f;

    for (int j0 = beg + w * 2; j0 < end; j0 += 8) {
        int sA = __builtin_amdgcn_readfirstlane((int)list[j0]);
        const bool hasB = (j0 + 1) < end;        // wave-uniform
        int sB = sA;
        if (hasB) sB = __builtin_amdgcn_readfirstlane((int)list[j0 + 1]);
        int slot = (sub == 1) ? sB : sA;
        uint4 v = *(const uint4*)(cmp + (size_t)slot * 100 + laneOff);
        bool act = (sub == 0) || ((sub == 1) && hasB);
        if (act) {
            a0 += asf(v.x << 16); a1 += asf(v.x & 0xFFFF0000u);
            a2 += asf(v.y << 16); a3 += asf(v.y & 0xFFFF0000u);
            a4 += asf(v.z << 16); a5 += asf(v.z & 0xFFFF0000u);
            a6 += asf(v.w << 16); a7 += asf(v.w & 0xFFFF0000u);
        }
    }

    if (sub < 2) {
        int row = w * 2 + sub;
        int c = w25 * 8;
        red[row][c]     = a0; red[row][c + 1] = a1;
        red[row][c + 2] = a2; red[row][c + 3] = a3;
        red[row][c + 4] = a4; red[row][c + 5] = a5;
        red[row][c + 6] = a6; red[row][c + 7] = a7;
    }
    __syncthreads();

    if (tid < DD) {
        float s = 0.f;
        #pragma unroll
        for (int q = 0; q < 8; ++q) s += red[q][tid];
        partial[(size_t)b * DD + tid] = f2bf(s);
    }
}

// -------- batched GEMV (8 relations/block) + GRU combine + write --------
__launch_bounds__(256)
__global__ void gemv_gru8_kernel(const uint16* __restrict__ partial, // (nbuk,200) bf16
                                 const float* __restrict__ dyn,      // (R,1,D,2)
                                 const float* __restrict__ WT_ih,    // (D,3D)
                                 const float* __restrict__ WT_hh,
                                 const float* __restrict__ b_ih,
                                 const float* __restrict__ b_hh,
                                 const int* __restrict__ offs,
                                 float* __restrict__ out,            // (R,1,D,2)
                                 int NGP) {
    const int x    = blockIdx.x;      // relation octet
    const int side = blockIdx.y;
    const int tid  = threadIdx.x;

    __shared__ float xs[8][DD];
    __shared__ float hs[8][DD];
    __shared__ float gi[8][DD3];
    __shared__ float gh[8][DD3];

    #pragma unroll
    for (int rr = 0; rr < 8; ++rr) {
        int r = x * 8 + rr;
        int bb = (r * 2 + side) * NGP;
        if (tid < DD) {
            int n = offs[bb + NGP] - offs[bb];
            float s = 0.f;
            for (int g = 0; g < NGP; ++g)
                s += bf2f(partial[(size_t)(bb + g) * DD + tid]);
            xs[rr][tid] = (n > 0) ? s / (float)n : 0.f;
            hs[rr][tid] = dyn[((size_t)r * DD + tid) * 2 + side];
        }
    }
    __syncthreads();

    {
        float aI0[8], aI1[8], aI2[8], aH0[8], aH1[8], aH2[8];
        #pragma unroll
        for (int rr = 0; rr < 8; ++rr) {
            aI0[rr] = aI1[rr] = aI2[rr] = 0.f;
            aH0[rr] = aH1[rr] = aH2[rr] = 0.f;
        }
        const bool has2 = tid < (DD3 - 512);   // tid < 88
        for (int k = 0; k < DD; ++k) {
            const float* rI = WT_ih + k * DD3;
            const float* rH = WT_hh + k * DD3;
            float wi0 = rI[tid], wi1 = rI[tid + 256];
            float wh0 = rH[tid], wh1 = rH[tid + 256];
            float wi2 = has2 ? rI[tid + 512] : 0.f;
            float wh2 = has2 ? rH[tid + 512] : 0.f;
            #pragma unroll
            for (int rr = 0; rr < 8; ++rr) {
                float xv = xs[rr][k];
                float hv = hs[rr][k];
                aI0[rr] = fmaf(xv, wi0, aI0[rr]);
                aI1[rr] = fmaf(xv, wi1, aI1[rr]);
                aI2[rr] = fmaf(xv, wi2, aI2[rr]);
                aH0[rr] = fmaf(hv, wh0, aH0[rr]);
                aH1[rr] = fmaf(hv, wh1, aH1[rr]);
                aH2[rr] = fmaf(hv, wh2, aH2[rr]);
            }
        }
        #pragma unroll
        for (int rr = 0; rr < 8; ++rr) {
            gi[rr][tid]       = aI0[rr] + b_ih[tid];
            gh[rr][tid]       = aH0[rr] + b_hh[tid];
            gi[rr][tid + 256] = aI1[rr] + b_ih[tid + 256];
            gh[rr][tid + 256] = aH1[rr] + b_hh[tid + 256];
            if (has2) {
                gi[rr][tid + 512] = aI2[rr] + b_ih[tid + 512];
                gh[rr][tid + 512] = aH2[rr] + b_hh[tid + 512];
            }
        }
    }
    __syncthreads();

    if (tid < DD) {
        #pragma unroll
        for (int rr = 0; rr < 8; ++rr) {
            int r = x * 8 + rr;
            float rg = 1.f / (1.f + __expf(-(gi[rr][tid] + gh[rr][tid])));
            float zz = 1.f / (1.f + __expf(-(gi[rr][DD + tid] + gh[rr][DD + tid])));
            float nn = tanhf(gi[rr][2 * DD + tid] + rg * gh[rr][2 * DD + tid]);
            out[((size_t)r * DD + tid) * 2 + side] = (1.f - zz) * nn + zz * hs[rr][tid];
        }
    }
}

// ================= fallback path (tiny ws): atomics into d_out ================
__global__ void hist_kernel(const int* __restrict__ etype, int* __restrict__ cnt,
                            int E, int R) {
    __shared__ int lc[1024];
    for (int i = threadIdx.x; i < R; i += blockDim.x) lc[i] = 0;
    __syncthreads();
    int stride = gridDim.x * blockDim.x;
    for (int i = blockIdx.x * blockDim.x + threadIdx.x; i < E; i += stride)
        atomicAdd(&lc[etype[i]], 1);
    __syncthreads();
    for (int i = threadIdx.x; i < R; i += blockDim.x)
        if (lc[i]) atomicAdd(&cnt[i], lc[i]);
}

__global__ void atomic_acc_kernel(const int* __restrict__ eidx, const int* __restrict__ etype,
                                  const int* __restrict__ node_id, const float* __restrict__ emb,
                                  float* __restrict__ acc, int E) {
    int gtid = blockIdx.x * blockDim.x + threadIdx.x;
    int wave = gtid >> 6, lane = gtid & 63;
    int nwaves = (gridDim.x * blockDim.x) >> 6;
    for (int e = wave; e < E; e += nwaves) {
        int r = etype[e];
        float* dst = acc + (size_t)r * DD * 2;
        for (int side = 0; side < 2; ++side) {
            int nid = node_id[eidx[(size_t)side * E + e]];
            const float* row = emb + (size_t)nid * DD;
            for (int d = lane; d < DD; d += 64)
                atomicAdd(&dst[d * 2 + side], row[d]);
        }
    }
}

__launch_bounds__(256)
__global__ void gru_inplace_kernel(const float* __restrict__ dyn, const float* __restrict__ W_ih,
                                   const float* __restrict__ W_hh, const float* __restrict__ b_ih,
                                   const float* __restrict__ b_hh, const int* __restrict__ cnt,
                                   float* __restrict__ out) {
    const int r = blockIdx.x, side = blockIdx.y, tid = threadIdx.x;
    __shared__ float xs[DD], hs[DD], gi[DD3], gh[DD3];
    if (tid < DD) {
        float s = out[((size_t)r * DD + tid) * 2 + side];
        int n = cnt[r];
        xs[tid] = (n > 0) ? s / (float)n : 0.f;
        hs[tid] = dyn[((size_t)r * DD + tid) * 2 + side];
    }
    __syncthreads();
    for (int jj = tid; jj < DD3; jj += 256) {
        float a = b_ih[jj], c = b_hh[jj];
        const float* rI = W_ih + (size_t)jj * DD;
        const float* rH = W_hh + (size_t)jj * DD;
        for (int k = 0; k < DD; ++k) { a = fmaf(xs[k], rI[k], a); c = fmaf(hs[k], rH[k], c); }
        gi[jj] = a; gh[jj] = c;
    }
    __syncthreads();
    if (tid < DD) {
        float rr = 1.f / (1.f + __expf(-(gi[tid] + gh[tid])));
        float zz = 1.f / (1.f + __expf(-(gi[DD + tid] + gh[DD + tid])));
        float nn = tanhf(gi[2 * DD + tid] + rr * gh[2 * DD + tid]);
        out[((size_t)r * DD + tid) * 2 + side] = (1.f - zz) * nn + zz * hs[tid];
    }
}

extern "C" void kernel_launch(void* const* d_in, const int* in_sizes, int n_in,
                              void* d_out, int out_size, void* d_ws, size_t ws_size,
                              hipStream_t stream) {
    const int*   eidx    = (const int*)d_in[0];
    const int*   etype   = (const int*)d_in[1];
    const int*   node_id = (const int*)d_in[2];
    const float* emb     = (const float*)d_in[3];
    const float* dyn     = (const float*)d_in[4];
    const float* W_ih    = (const float*)d_in[5];
    const float* W_hh    = (const float*)d_in[6];
    const float* b_ih    = (const float*)d_in[7];
    const float* b_hh    = (const float*)d_in[8];
    float*       out     = (float*)d_out;

    const int E  = in_sizes[1];
    const int NB = in_sizes[2];                // 50,000
    const int D  = in_sizes[7] / 3;            // 200
    const int R  = in_sizes[4] / (2 * D);      // 1000
    const int D3 = 3 * D;                      // 600

    // Try NGP=8 first (XCD-local slices), fall back to NGP=4, then atomics.
    for (int NGP = 8; NGP >= 4; NGP -= 4) {
        // SSHIFT: smallest shift with (NB-1)>>SSHIFT < NGP
        int SSHIFT = 0;
        while (((NB - 1) >> SSHIFT) >= NGP) ++SSHIFT;
        const int nbuk = R * 2 * NGP;

        char* p = (char*)d_ws;
        auto take = [&](size_t bytes) { char* q = p; p += (bytes + 255) & ~(size_t)255; return q; };
        int*    cnt     = (int*)   take((size_t)nbuk * 4);
        int*    cursor  = (int*)   take((size_t)nbuk * 4);
        int*    offs    = (int*)   take((size_t)(nbuk + 1) * 4);
        uint16* list    = (uint16*)take((size_t)2 * E * 2);          // 4 MB
        uint32* cmp     = (uint32*)take((size_t)NB * 100 * 4);       // 20 MB
        uint16* partial = (uint16*)take((size_t)nbuk * D * 2);       // 6.4 / 3.2 MB
        size_t need_base = (size_t)(p - (char*)d_ws);
        float* WT_ih;
        float* WT_hh;
        size_t wt_bytes = ((size_t)D3 * D * 4 + 255) & ~(size_t)255;
        if (ws_size >= need_base + 2 * wt_bytes) {
            WT_ih = (float*)take(wt_bytes);
            WT_hh = (float*)take(wt_bytes);
        } else {
            // overlay onto list region (list dead after partial6; transpose2 runs after)
            WT_ih = (float*)list;
            WT_hh = (float*)((char*)list + wt_bytes);
        }

        const bool fits = (ws_size >= need_base) && (NB <= 65535) && (R == 1000) &&
                          (D == 200) && (nbuk <= MAXBUK) && ((R & 7) == 0);
        if (!fits) continue;

        zero_kernel<<<32, 256, 0, stream>>>(cnt, nbuk);
        hist6_kernel<<<64, 1024, 0, stream>>>(etype, eidx, cnt, E, SSHIFT, NGP, nbuk);
        scan6_kernel<<<1, 1024, 0, stream>>>(cnt, offs, cursor, nbuk);
        scatter6_kernel<<<1024, 256, 0, stream>>>(etype, eidx, cursor, list, E, SSHIFT, NGP);
        int cw = (NB * 50 + 255) / 256;
        compact6_kernel<<<cw, 256, 0, stream>>>(node_id, emb, cmp, NB);
        partial6_kernel<<<nbuk, 256, 0, stream>>>(list, cmp, offs, partial);
        int tw = (2 * D3 * D + 255) / 256;
        transpose2_kernel<<<tw, 256, 0, stream>>>(W_ih, W_hh, WT_ih, WT_hh, D3, D);
        dim3 grid(R / 8, 2);
        gemv_gru8_kernel<<<grid, 256, 0, stream>>>(partial, dyn, WT_ih, WT_hh,
                                                   b_ih, b_hh, offs, out, NGP);
        return;
    }

    // ---- last resort: tiny ws, atomics into d_out ----
    int* cnt = (int*)d_ws;
    zero_kernel<<<32, 256, 0, stream>>>(cnt, R);
    hist_kernel<<<512, 256, 0, stream>>>(etype, cnt, E, R);
    zerof_kernel<<<(R * D * 2 + 255) / 256, 256, 0, stream>>>(out, R * D * 2);
    atomic_acc_kernel<<<2048, 256, 0, stream>>>(eidx, etype, node_id, emb, out, E);
    dim3 grid(R, 2);
    gru_inplace_kernel<<<grid, 256, 0, stream>>>(dyn, W_ih, W_hh, b_ih, b_hh, cnt, out);
}

// Round 8
// 272.641 us; speedup vs baseline: 1.2003x; 1.2003x over previous
//
#include <hip/hip_runtime.h>
#include <math.h>

// Problem constants: E=1,000,000  R=1000  D=200  N_BATCH=50,000  N_TOTAL=100,000
#define DD     200
#define DD3    600
#define MAXBUK 16000   // R*2*NGP upper bound (LDS histogram size)
#define CHUNK  1024    // slot-staging chunk (uint16 -> 2KB LDS)

typedef unsigned int   uint32;
typedef unsigned short uint16;

static __device__ inline float bf2f(uint16 u) {
    union { uint32 i; float f; } x; x.i = ((uint32)u) << 16; return x.f;
}
static __device__ inline uint16 f2bf(float f) {
    union { float f; uint32 i; } x; x.f = f;
    return (uint16)((x.i + 0x7FFFu + ((x.i >> 16) & 1u)) >> 16);
}
static __device__ inline float asf(uint32 u) {
    union { uint32 i; float f; } x; x.i = u; return x.f;
}
static __device__ inline uint32 packbf(float a, float b) {
    return (uint32)f2bf(a) | ((uint32)f2bf(b) << 16);
}

// ---------------- zero int counters (grid-stride) ----------------
__global__ void zero_kernel(int* __restrict__ cnt, int n) {
    int stride = gridDim.x * blockDim.x;
    for (int i = blockIdx.x * blockDim.x + threadIdx.x; i < n; i += stride) cnt[i] = 0;
}

// ---------------- zero float buffer ----------------
__global__ void zerof_kernel(float* __restrict__ p, int n) {
    int stride = gridDim.x * blockDim.x;
    for (int i = blockIdx.x * blockDim.x + threadIdx.x; i < n; i += stride) p[i] = 0.f;
}

// -------- hist over (relation, side, slot>>SSHIFT): nbuk bins, LDS-staged --------
__launch_bounds__(1024)
__global__ void hist6_kernel(const int* __restrict__ etype, const int* __restrict__ eidx,
                             int* __restrict__ cnt, int E, int SSHIFT, int NGP, int nbuk) {
    __shared__ int lc[MAXBUK];
    for (int i = threadIdx.x; i < nbuk; i += 1024) lc[i] = 0;
    __syncthreads();
    int per = (E + gridDim.x - 1) / gridDim.x;
    int beg = blockIdx.x * per;
    int end = min(E, beg + per);
    for (int e = beg + (int)threadIdx.x; e < end; e += 1024) {
        int r  = etype[e];
        int gS = eidx[e] >> SSHIFT;
        int gD = eidx[E + e] >> SSHIFT;
        atomicAdd(&lc[r * (2 * NGP) + gS], 1);
        atomicAdd(&lc[r * (2 * NGP) + NGP + gD], 1);
    }
    __syncthreads();
    for (int i = threadIdx.x; i < nbuk; i += 1024)
        if (lc[i]) atomicAdd(&cnt[i], lc[i]);
}

// ---- exclusive scan, single block, 16/thread + one 1024-wide block scan ----
__launch_bounds__(1024)
__global__ void scan6_kernel(const int* __restrict__ cnt, int* __restrict__ offs,
                             int* __restrict__ cursor, int n) {
    __shared__ int s[1024];
    int tid = threadIdx.x;
    int base = tid * 16;
    int v[16];
    int sum = 0;
    #pragma unroll
    for (int i = 0; i < 16; ++i) {
        int idx = base + i;
        v[i] = (idx < n) ? cnt[idx] : 0;
        sum += v[i];
    }
    s[tid] = sum;
    for (int off = 1; off < 1024; off <<= 1) {
        __syncthreads();
        int t = (tid >= off) ? s[tid - off] : 0;
        __syncthreads();
        s[tid] += t;
    }
    __syncthreads();
    int excl = s[tid] - sum;
    #pragma unroll
    for (int i = 0; i < 16; ++i) {
        int idx = base + i;
        if (idx < n) { offs[idx] = excl; cursor[idx] = excl; }
        excl += v[i];
    }
    if (tid == 1023) offs[n] = excl;
}

// -------- scatter: slot (uint16) into (r, side, group) buckets --------
__global__ void scatter6_kernel(const int* __restrict__ etype, const int* __restrict__ eidx,
                                int* __restrict__ cursor, uint16* __restrict__ list,
                                int E, int SSHIFT, int NGP) {
    int stride = gridDim.x * blockDim.x;
    for (int i = blockIdx.x * blockDim.x + threadIdx.x; i < E; i += stride) {
        int r  = etype[i];
        int sS = eidx[i];
        int sD = eidx[E + i];
        int pS = atomicAdd(&cursor[r * (2 * NGP) + (sS >> SSHIFT)], 1);
        list[pS] = (uint16)sS;
        int pD = atomicAdd(&cursor[r * (2 * NGP) + NGP + (sD >> SSHIFT)], 1);
        list[pD] = (uint16)sD;
    }
}

// ---- fused prep: compact rows to bf16 + transpose both W matrices ----
__global__ void prep_kernel(const int* __restrict__ node_id, const float* __restrict__ emb,
                            uint32* __restrict__ cmp, int NB,
                            const float* __restrict__ A, const float* __restrict__ B,
                            float* __restrict__ TA, float* __restrict__ TB,
                            int rows, int cols) {
    int idx = blockIdx.x * blockDim.x + threadIdx.x;
    int nc = NB * 50;
    int nt = rows * cols;
    if (idx < nc) {
        int s = idx / 50, q = idx - s * 50;        // q in [0,50): dims 4q..4q+3
        int nid = node_id[s];
        float4 v = *(const float4*)(emb + (size_t)nid * DD + 4 * q);
        *(uint2*)(cmp + (size_t)s * 100 + 2 * q) = make_uint2(packbf(v.x, v.y), packbf(v.z, v.w));
    } else if (idx < nc + nt) {
        int k = idx - nc;
        int j = k / cols, d = k % cols;
        TA[d * rows + j] = A[k];
    } else if (idx < nc + 2 * nt) {
        int k = idx - nc - nt;
        int j = k / cols, d = k % cols;
        TB[d * rows + j] = B[k];
    }
}

// -------- partial sums: block = bucket b; b%NGP = slot-group -> XCD-local slice --------
// Full 400B rows, 2 entries/wave (lanes 0-24 entry A, 25-49 entry B, uint4/lane).
// Slot list staged in LDS (kills list-load latency hop); gather 2x unrolled for ILP.
__launch_bounds__(256)
__global__ void partial7_kernel(const uint16* __restrict__ list,
                                const uint32* __restrict__ cmp,
                                const int* __restrict__ offs,
                                uint16* __restrict__ partial) {  // (nbuk, 200) bf16 sums
    const int b    = blockIdx.x;
    const int tid  = threadIdx.x;
    const int w    = tid >> 6;
    const int lane = tid & 63;
    const int sub  = lane / 25;        // 0: entry A, 1: entry B, 2: idle
    const int w25  = lane % 25;        // uint4 index within row
    const int laneOff = w25 * 4;       // uint32 offset within row

    __shared__ uint16 sl[CHUNK];
    __shared__ float  red[8][DD];

    const int beg = offs[b];
    const int end = offs[b + 1];

    float a0 = 0.f, a1 = 0.f, a2 = 0.f, a3 = 0.f, a4 = 0.f, a5 = 0.f, a6 = 0.f, a7 = 0.f;

    for (int base = beg; base < end; base += CHUNK) {
        const int m = min(CHUNK, end - base);
        for (int i = tid; i < m; i += 256) sl[i] = list[base + i];
        __syncthreads();
        if (sub < 2) {
            int i = w * 2 + sub;
            for (; i + 8 < m; i += 16) {       // 2 independent gathers in flight
                int s0 = sl[i];
                int s1 = sl[i + 8];
                uint4 v0 = *(const uint4*)(cmp + (size_t)s0 * 100 + laneOff);
                uint4 v1 = *(const uint4*)(cmp + (size_t)s1 * 100 + laneOff);
                a0 += asf(v0.x << 16) + asf(v1.x << 16);
                a1 += asf(v0.x & 0xFFFF0000u) + asf(v1.x & 0xFFFF0000u);
                a2 += asf(v0.y << 16) + asf(v1.y << 16);
                a3 += asf(v0.y & 0xFFFF0000u) + asf(v1.y & 0xFFFF0000u);
                a4 += asf(v0.z << 16) + asf(v1.z << 16);
                a5 += asf(v0.z & 0xFFFF0000u) + asf(v1.z & 0xFFFF0000u);
                a6 += asf(v0.w << 16) + asf(v1.w << 16);
                a7 += asf(v0.w & 0xFFFF0000u) + asf(v1.w & 0xFFFF0000u);
            }
            for (; i < m; i += 8) {
                int s0 = sl[i];
                uint4 v0 = *(const uint4*)(cmp + (size_t)s0 * 100 + laneOff);
                a0 += asf(v0.x << 16); a1 += asf(v0.x & 0xFFFF0000u);
                a2 += asf(v0.y << 16); a3 += asf(v0.y & 0xFFFF0000u);
                a4 += asf(v0.z << 16); a5 += asf(v0.z & 0xFFFF0000u);
                a6 += asf(v0.w << 16); a7 += asf(v0.w & 0xFFFF0000u);
            }
        }
        __syncthreads();
    }

    if (sub < 2) {
        int row = w * 2 + sub;
        int c = w25 * 8;
        red[row][c]     = a0; red[row][c + 1] = a1;
        red[row][c + 2] = a2; red[row][c + 3] = a3;
        red[row][c + 4] = a4; red[row][c + 5] = a5;
        red[row][c + 6] = a6; red[row][c + 7] = a7;
    }
    __syncthreads();

    if (tid < DD) {
        float s = 0.f;
        #pragma unroll
        for (int q = 0; q < 8; ++q) s += red[q][tid];
        partial[(size_t)b * DD + tid] = f2bf(s);
    }
}

// -------- batched GEMV (8 relations/block) + GRU combine + write --------
__launch_bounds__(256)
__global__ void gemv_gru8_kernel(const uint16* __restrict__ partial, // (nbuk,200) bf16
                                 const float* __restrict__ dyn,      // (R,1,D,2)
                                 const float* __restrict__ WT_ih,    // (D,3D)
                                 const float* __restrict__ WT_hh,
                                 const float* __restrict__ b_ih,
                                 const float* __restrict__ b_hh,
                                 const int* __restrict__ offs,
                                 float* __restrict__ out,            // (R,1,D,2)
                                 int NGP) {
    const int x    = blockIdx.x;      // relation octet
    const int side = blockIdx.y;
    const int tid  = threadIdx.x;

    __shared__ float xs[8][DD];
    __shared__ float hs[8][DD];
    __shared__ float gi[8][DD3];
    __shared__ float gh[8][DD3];

    #pragma unroll
    for (int rr = 0; rr < 8; ++rr) {
        int r = x * 8 + rr;
        int bb = (r * 2 + side) * NGP;
        if (tid < DD) {
            int n = offs[bb + NGP] - offs[bb];
            float s = 0.f;
            for (int g = 0; g < NGP; ++g)
                s += bf2f(partial[(size_t)(bb + g) * DD + tid]);
            xs[rr][tid] = (n > 0) ? s / (float)n : 0.f;
            hs[rr][tid] = dyn[((size_t)r * DD + tid) * 2 + side];
        }
    }
    __syncthreads();

    {
        float aI0[8], aI1[8], aI2[8], aH0[8], aH1[8], aH2[8];
        #pragma unroll
        for (int rr = 0; rr < 8; ++rr) {
            aI0[rr] = aI1[rr] = aI2[rr] = 0.f;
            aH0[rr] = aH1[rr] = aH2[rr] = 0.f;
        }
        const bool has2 = tid < (DD3 - 512);   // tid < 88
        for (int k = 0; k < DD; ++k) {
            const float* rI = WT_ih + k * DD3;
            const float* rH = WT_hh + k * DD3;
            float wi0 = rI[tid], wi1 = rI[tid + 256];
            float wh0 = rH[tid], wh1 = rH[tid + 256];
            float wi2 = has2 ? rI[tid + 512] : 0.f;
            float wh2 = has2 ? rH[tid + 512] : 0.f;
            #pragma unroll
            for (int rr = 0; rr < 8; ++rr) {
                float xv = xs[rr][k];
                float hv = hs[rr][k];
                aI0[rr] = fmaf(xv, wi0, aI0[rr]);
                aI1[rr] = fmaf(xv, wi1, aI1[rr]);
                aI2[rr] = fmaf(xv, wi2, aI2[rr]);
                aH0[rr] = fmaf(hv, wh0, aH0[rr]);
                aH1[rr] = fmaf(hv, wh1, aH1[rr]);
                aH2[rr] = fmaf(hv, wh2, aH2[rr]);
            }
        }
        #pragma unroll
        for (int rr = 0; rr < 8; ++rr) {
            gi[rr][tid]       = aI0[rr] + b_ih[tid];
            gh[rr][tid]       = aH0[rr] + b_hh[tid];
            gi[rr][tid + 256] = aI1[rr] + b_ih[tid + 256];
            gh[rr][tid + 256] = aH1[rr] + b_hh[tid + 256];
            if (has2) {
                gi[rr][tid + 512] = aI2[rr] + b_ih[tid + 512];
                gh[rr][tid + 512] = aH2[rr] + b_hh[tid + 512];
            }
        }
    }
    __syncthreads();

    if (tid < DD) {
        #pragma unroll
        for (int rr = 0; rr < 8; ++rr) {
            int r = x * 8 + rr;
            float rg = 1.f / (1.f + __expf(-(gi[rr][tid] + gh[rr][tid])));
            float zz = 1.f / (1.f + __expf(-(gi[rr][DD + tid] + gh[rr][DD + tid])));
            float nn = tanhf(gi[rr][2 * DD + tid] + rg * gh[rr][2 * DD + tid]);
            out[((size_t)r * DD + tid) * 2 + side] = (1.f - zz) * nn + zz * hs[rr][tid];
        }
    }
}

// ================= fallback path (tiny ws): atomics into d_out ================
__global__ void hist_kernel(const int* __restrict__ etype, int* __restrict__ cnt,
                            int E, int R) {
    __shared__ int lc[1024];
    for (int i = threadIdx.x; i < R; i += blockDim.x) lc[i] = 0;
    __syncthreads();
    int stride = gridDim.x * blockDim.x;
    for (int i = blockIdx.x * blockDim.x + threadIdx.x; i < E; i += stride)
        atomicAdd(&lc[etype[i]], 1);
    __syncthreads();
    for (int i = threadIdx.x; i < R; i += blockDim.x)
        if (lc[i]) atomicAdd(&cnt[i], lc[i]);
}

__global__ void atomic_acc_kernel(const int* __restrict__ eidx, const int* __restrict__ etype,
                                  const int* __restrict__ node_id, const float* __restrict__ emb,
                                  float* __restrict__ acc, int E) {
    int gtid = blockIdx.x * blockDim.x + threadIdx.x;
    int wave = gtid >> 6, lane = gtid & 63;
    int nwaves = (gridDim.x * blockDim.x) >> 6;
    for (int e = wave; e < E; e += nwaves) {
        int r = etype[e];
        float* dst = acc + (size_t)r * DD * 2;
        for (int side = 0; side < 2; ++side) {
            int nid = node_id[eidx[(size_t)side * E + e]];
            const float* row = emb + (size_t)nid * DD;
            for (int d = lane; d < DD; d += 64)
                atomicAdd(&dst[d * 2 + side], row[d]);
        }
    }
}

__launch_bounds__(256)
__global__ void gru_inplace_kernel(const float* __restrict__ dyn, const float* __restrict__ W_ih,
                                   const float* __restrict__ W_hh, const float* __restrict__ b_ih,
                                   const float* __restrict__ b_hh, const int* __restrict__ cnt,
                                   float* __restrict__ out) {
    const int r = blockIdx.x, side = blockIdx.y, tid = threadIdx.x;
    __shared__ float xs[DD], hs[DD], gi[DD3], gh[DD3];
    if (tid < DD) {
        float s = out[((size_t)r * DD + tid) * 2 + side];
        int n = cnt[r];
        xs[tid] = (n > 0) ? s / (float)n : 0.f;
        hs[tid] = dyn[((size_t)r * DD + tid) * 2 + side];
    }
    __syncthreads();
    for (int jj = tid; jj < DD3; jj += 256) {
        float a = b_ih[jj], c = b_hh[jj];
        const float* rI = W_ih + (size_t)jj * DD;
        const float* rH = W_hh + (size_t)jj * DD;
        for (int k = 0; k < DD; ++k) { a = fmaf(xs[k], rI[k], a); c = fmaf(hs[k], rH[k], c); }
        gi[jj] = a; gh[jj] = c;
    }
    __syncthreads();
    if (tid < DD) {
        float rr = 1.f / (1.f + __expf(-(gi[tid] + gh[tid])));
        float zz = 1.f / (1.f + __expf(-(gi[DD + tid] + gh[DD + tid])));
        float nn = tanhf(gi[2 * DD + tid] + rr * gh[2 * DD + tid]);
        out[((size_t)r * DD + tid) * 2 + side] = (1.f - zz) * nn + zz * hs[tid];
    }
}

extern "C" void kernel_launch(void* const* d_in, const int* in_sizes, int n_in,
                              void* d_out, int out_size, void* d_ws, size_t ws_size,
                              hipStream_t stream) {
    const int*   eidx    = (const int*)d_in[0];
    const int*   etype   = (const int*)d_in[1];
    const int*   node_id = (const int*)d_in[2];
    const float* emb     = (const float*)d_in[3];
    const float* dyn     = (const float*)d_in[4];
    const float* W_ih    = (const float*)d_in[5];
    const float* W_hh    = (const float*)d_in[6];
    const float* b_ih    = (const float*)d_in[7];
    const float* b_hh    = (const float*)d_in[8];
    float*       out     = (float*)d_out;

    const int E  = in_sizes[1];
    const int NB = in_sizes[2];                // 50,000
    const int D  = in_sizes[7] / 3;            // 200
    const int R  = in_sizes[4] / (2 * D);      // 1000
    const int D3 = 3 * D;                      // 600

    // Try NGP=8 first (XCD-local slices), fall back to NGP=4, then atomics.
    for (int NGP = 8; NGP >= 4; NGP -= 4) {
        // SSHIFT: smallest shift with (NB-1)>>SSHIFT < NGP
        int SSHIFT = 0;
        while (((NB - 1) >> SSHIFT) >= NGP) ++SSHIFT;
        const int nbuk = R * 2 * NGP;

        char* p = (char*)d_ws;
        auto take = [&](size_t bytes) { char* q = p; p += (bytes + 255) & ~(size_t)255; return q; };
        int*    cnt     = (int*)   take((size_t)nbuk * 4);
        int*    cursor  = (int*)   take((size_t)nbuk * 4);
        int*    offs    = (int*)   take((size_t)(nbuk + 1) * 4);
        uint16* list    = (uint16*)take((size_t)2 * E * 2);          // 4 MB
        uint32* cmp     = (uint32*)take((size_t)NB * 100 * 4);       // 20 MB
        uint16* partial = (uint16*)take((size_t)nbuk * D * 2);       // 6.4 / 3.2 MB
        size_t need_base = (size_t)(p - (char*)d_ws);
        float* WT_ih;
        float* WT_hh;
        size_t wt_bytes = ((size_t)D3 * D * 4 + 255) & ~(size_t)255;
        if (ws_size >= need_base + 2 * wt_bytes) {
            WT_ih = (float*)take(wt_bytes);
            WT_hh = (float*)take(wt_bytes);
        } else {
            // overlay onto list region (list dead after partial7; prep's transpose
            // output is only read by gemv which launches after partial7)
            WT_ih = (float*)list;
            WT_hh = (float*)((char*)list + wt_bytes);
        }
        // NOTE: if overlaying, prep_kernel writes WT into the list region BEFORE
        // partial7 reads list -> forbidden. Guard: only overlay if not needed.
        const bool overlay = !(ws_size >= need_base + 2 * wt_bytes);

        const bool fits = (ws_size >= need_base) && (NB <= 65535) && (R == 1000) &&
                          (D == 200) && (nbuk <= MAXBUK) && ((R & 7) == 0) && !overlay;
        if (!fits) continue;

        zero_kernel<<<32, 256, 0, stream>>>(cnt, nbuk);
        hist6_kernel<<<128, 1024, 0, stream>>>(etype, eidx, cnt, E, SSHIFT, NGP, nbuk);
        scan6_kernel<<<1, 1024, 0, stream>>>(cnt, offs, cursor, nbuk);
        scatter6_kernel<<<1024, 256, 0, stream>>>(etype, eidx, cursor, list, E, SSHIFT, NGP);
        int pw = (NB * 50 + 2 * D3 * D + 255) / 256;
        prep_kernel<<<pw, 256, 0, stream>>>(node_id, emb, cmp, NB,
                                            W_ih, W_hh, WT_ih, WT_hh, D3, D);
        partial7_kernel<<<nbuk, 256, 0, stream>>>(list, cmp, offs, partial);
        dim3 grid(R / 8, 2);
        gemv_gru8_kernel<<<grid, 256, 0, stream>>>(partial, dyn, WT_ih, WT_hh,
                                                   b_ih, b_hh, offs, out, NGP);
        return;
    }

    // ---- last resort: tiny ws, atomics into d_out ----
    int* cnt = (int*)d_ws;
    zero_kernel<<<32, 256, 0, stream>>>(cnt, R);
    hist_kernel<<<512, 256, 0, stream>>>(etype, cnt, E, R);
    zerof_kernel<<<(R * D * 2 + 255) / 256, 256, 0, stream>>>(out, R * D * 2);
    atomic_acc_kernel<<<2048, 256, 0, stream>>>(eidx, etype, node_id, emb, out, E);
    dim3 grid(R, 2);
    gru_inplace_kernel<<<grid, 256, 0, stream>>>(dyn, W_ih, W_hh, b_ih, b_hh, cnt, out);
}